// Round 6
// baseline (392.415 us; speedup 1.0000x reference)
//
#include <hip/hip_runtime.h>

#define SEQ  3072
#define HID  1280
#define NH   16
#define HD   80
#define NQKV 3840
#define KSP  3
#define QT   192
#define KCHUNK 1024   // SEQ/KSP
#define NT   16       // KCHUNK/64

typedef unsigned short u16;
typedef unsigned int u32;
typedef __attribute__((ext_vector_type(8))) short short8;
typedef __attribute__((ext_vector_type(4))) short short4v;
typedef __attribute__((ext_vector_type(4))) float floatx4;

__device__ __forceinline__ u16 f2bf(float x) {
    u32 u = __float_as_uint(x);
    u += 0x7fffu + ((u >> 16) & 1u);
    return (u16)(u >> 16);
}
__device__ __forceinline__ u32 packrne(float a, float b) {
    return (u32)f2bf(a) | ((u32)f2bf(b) << 16);
}

typedef const __attribute__((address_space(1))) unsigned int* gp1_t;
typedef __attribute__((address_space(3))) unsigned int* lp3_t;
__device__ __forceinline__ void gld16(const void* g, void* l) {
    __builtin_amdgcn_global_load_lds((gp1_t)g, (lp3_t)l, 16, 0, 0);
}

// swizzled 16B-chunk position for 80-dim Q/K rows (10 chunks / 160B):
// main chunks 0..7: ^(r&7); tail 8..9: ^((r>>2)&1)
__device__ __forceinline__ int swz80(int c, int r) {
    return (c < 8) ? (c ^ (r & 7)) : (8 + ((c - 8) ^ ((r >> 2) & 1)));
}

// ---------------- fused prep: rope tables | cast hidden | transpose qkv_w | transpose o_w ----------------
__global__ void prep_k(const int* __restrict__ pos, float* __restrict__ cosb,
                       float* __restrict__ sinb, const float* __restrict__ hs,
                       u16* __restrict__ hH, const float* __restrict__ qkvw,
                       u16* __restrict__ wT, const float* __restrict__ ow,
                       u16* __restrict__ owT) {
    __shared__ float tile[32][33];
    const int b = blockIdx.x, t = threadIdx.x;
    if (b < 480) {  // rope tables: 3072 x 40
        int i = b * 256 + t;
        int s = i / 40, j = i % 40;
        float p = (float)((j < 20) ? pos[s * 2] : pos[s * 2 + 1]);
        int k = (j < 20) ? j : j - 20;
        float inv = powf(10000.0f, -(float)k / 20.0f);
        float a = p * inv;
        cosb[s * 40 + j] = cosf(a);
        sinb[s * 40 + j] = sinf(a);
    } else if (b < 4320) {  // cast hidden f32 -> bf16, vec4
        int i = (b - 480) * 256 + t;  // < 983040
        const float4 x = ((const float4*)hs)[i];
        uint2 o;
        o.x = packrne(x.x, x.y);
        o.y = packrne(x.z, x.w);
        ((uint2*)hH)[i] = o;
    } else {
        const float* w;
        u16* dst;
        int K, N, nx, ky;
        if (b < 9120) {
            int i = b - 4320;
            nx = i % 120; ky = i / 120; w = qkvw; dst = wT; K = HID; N = NQKV;
        } else {
            int i = b - 9120;
            nx = i % 40; ky = i / 40; w = ow; dst = owT; K = HID; N = HID;
        }
        int n0 = nx * 32, k0 = ky * 32;
        int c = t & 31, r8 = t >> 5;
        for (int rr = r8; rr < 32; rr += 8)
            tile[rr][c] = w[(size_t)(k0 + rr) * N + n0 + c];
        __syncthreads();
        for (int rr = r8; rr < 32; rr += 8)
            dst[(size_t)(n0 + rr) * K + k0 + c] = f2bf(tile[c][rr]);
    }
}

// ---------------- bf16 GEMM: C[M][N] = A[M][K] * Bt[N][K]^T + bias, XCD-patched 1D grid ----------------
__global__ __launch_bounds__(256, 3) void gemm_bf16_k(
    const u16* __restrict__ A, const u16* __restrict__ B,
    const float* __restrict__ bias, float* __restrict__ C,
    int M, int N, int K, int mode) {
    __shared__ u16 lA[128 * 64], lB[128 * 64];
    const int t = threadIdx.x, lane = t & 63, w = t >> 6;
    const int qi = lane & 15, quad = lane >> 4;
    int id = blockIdx.x;
    int xcd = id & 7, sN = id >> 3;
    int m_idx, n_idx;
    if (mode == 0) {  // QKV: 30n x 24m tiles, 15x6 patch per XCD
        n_idx = (xcd & 1) * 15 + sN % 15;
        m_idx = (xcd >> 1) * 6 + sN / 15;
    } else {          // O-proj: 10n x 24m tiles, 10x3 patch per XCD
        m_idx = xcd * 3 + sN / 10;
        n_idx = sN % 10;
    }
    const int m0 = m_idx * 128, n0 = n_idx * 128;
    const int wm = (w >> 1) * 64, wn = (w & 1) * 64;

    floatx4 acc[4][4];
    for (int mi = 0; mi < 4; mi++)
        for (int ni = 0; ni < 4; ni++) acc[mi][ni] = (floatx4){0.f, 0.f, 0.f, 0.f};

    const int rg = lane >> 3;
    const int ce = ((lane & 7) ^ rg) * 8;
    size_t gA[4], gB[4];
    for (int g = 0; g < 4; g++) {
        int row = w * 32 + g * 8 + rg;
        gA[g] = (size_t)(m0 + row) * K + ce;
        gB[g] = (size_t)(n0 + row) * K + ce;
    }

    for (int k0 = 0; k0 < K; k0 += 64) {
        for (int g = 0; g < 4; g++) {
            gld16(A + gA[g] + k0, &lA[(w * 32 + g * 8) * 64]);
            gld16(B + gB[g] + k0, &lB[(w * 32 + g * 8) * 64]);
        }
        __syncthreads();
        short8 af[4][2], bf[4][2];
        for (int mi = 0; mi < 4; mi++) {
            int row = wm + mi * 16 + qi;
            for (int kh = 0; kh < 2; kh++)
                af[mi][kh] = *(const short8*)&lA[row * 64 + (((kh * 4 + quad) ^ (row & 7)) << 3)];
        }
        for (int ni = 0; ni < 4; ni++) {
            int row = wn + ni * 16 + qi;
            for (int kh = 0; kh < 2; kh++)
                bf[ni][kh] = *(const short8*)&lB[row * 64 + (((kh * 4 + quad) ^ (row & 7)) << 3)];
        }
        for (int mi = 0; mi < 4; mi++)
            for (int ni = 0; ni < 4; ni++) {
                acc[mi][ni] = __builtin_amdgcn_mfma_f32_16x16x32_bf16(af[mi][0], bf[ni][0], acc[mi][ni], 0, 0, 0);
                acc[mi][ni] = __builtin_amdgcn_mfma_f32_16x16x32_bf16(af[mi][1], bf[ni][1], acc[mi][ni], 0, 0, 0);
            }
        __syncthreads();
    }
    for (int mi = 0; mi < 4; mi++)
        for (int ni = 0; ni < 4; ni++) {
            int col = n0 + wn + ni * 16 + qi;
            int rowb = m0 + wm + mi * 16 + quad * 4;
            float b = bias[col];
            for (int r = 0; r < 4; r++)
                C[(size_t)(rowb + r) * N + col] = acc[mi][ni][r] + b;
        }
}

// ---------------- pack: rope Q (x scale x log2e), K -> swizzled [h][s][80]; V -> swizzled Vt ----------------
__global__ void pack_qkv_k(const float* __restrict__ qkv, const float* __restrict__ cosb,
                           const float* __restrict__ sinb,
                           u16* __restrict__ Qs, u16* __restrict__ Ks, u16* __restrict__ Vs) {
    __shared__ float lv[80 * 65];
    const int t = threadIdx.x;
    const int h = blockIdx.y, s0 = blockIdx.x * 64;
    const float qsc = 0.11180339887498949f * 1.4426950408889634f;  // 80^-0.5 * log2(e)

    for (int i = t; i < 64 * 10; i += 256) {
        int rl = i / 10, jg = i % 10;
        int s = s0 + rl, j = jg * 4;
        const float4 cc = *(const float4*)&cosb[s * 40 + j];
        const float4 ss = *(const float4*)&sinb[s * 40 + j];
        const float* qb = qkv + (size_t)s * NQKV + h * HD;
        const float4 q1 = *(const float4*)&qb[j];
        const float4 q2 = *(const float4*)&qb[j + 40];
        const float* kb = qb + HID;
        const float4 k1 = *(const float4*)&kb[j];
        const float4 k2 = *(const float4*)&kb[j + 40];
        uint2 qo1, qo2, ko1, ko2;
        qo1.x = packrne((q1.x * cc.x - q2.x * ss.x) * qsc, (q1.y * cc.y - q2.y * ss.y) * qsc);
        qo1.y = packrne((q1.z * cc.z - q2.z * ss.z) * qsc, (q1.w * cc.w - q2.w * ss.w) * qsc);
        qo2.x = packrne((q2.x * cc.x + q1.x * ss.x) * qsc, (q2.y * cc.y + q1.y * ss.y) * qsc);
        qo2.y = packrne((q2.z * cc.z + q1.z * ss.z) * qsc, (q2.w * cc.w + q1.w * ss.w) * qsc);
        ko1.x = packrne(k1.x * cc.x - k2.x * ss.x, k1.y * cc.y - k2.y * ss.y);
        ko1.y = packrne(k1.z * cc.z - k2.z * ss.z, k1.w * cc.w - k2.w * ss.w);
        ko2.x = packrne(k2.x * cc.x + k1.x * ss.x, k2.y * cc.y + k1.y * ss.y);
        ko2.y = packrne(k2.z * cc.z + k1.z * ss.z, k2.w * cc.w + k1.w * ss.w);
        size_t base = (size_t)(h * SEQ + s) * 80;
        int sub0 = j & 7, sub1 = (j + 40) & 7;
        int p0 = swz80(j >> 3, s);
        int p1 = swz80((j + 40) >> 3, s);
        *(uint2*)&Qs[base + p0 * 8 + sub0] = qo1;
        *(uint2*)&Qs[base + p1 * 8 + sub1] = qo2;
        *(uint2*)&Ks[base + p0 * 8 + sub0] = ko1;
        *(uint2*)&Ks[base + p1 * 8 + sub1] = ko2;
    }
    for (int i = t; i < 64 * 80; i += 256) {
        int rl = i / 80, d = i % 80;
        lv[d * 65 + rl] = qkv[(size_t)(s0 + rl) * NQKV + 2 * HID + h * HD + d];
    }
    __syncthreads();
    for (int i = t; i < 80 * 16; i += 256) {
        int d = i / 16, g = i % 16;
        int c2l = g * 4;
        float v0 = lv[d * 65 + c2l], v1 = lv[d * 65 + c2l + 1];
        float v2 = lv[d * 65 + c2l + 2], v3 = lv[d * 65 + c2l + 3];
        int pc = (g >> 1) ^ (d & 7);
        uint2 o;
        o.x = packrne(v0, v1);
        o.y = packrne(v2, v3);
        *(uint2*)&Vs[((size_t)h * HD + d) * SEQ + s0 + pc * 8 + (g & 1) * 4] = o;
    }
}

// ---------------- flash attention: QT=192 (3 qg), key-split 3, no-max exp2 softmax ----------------
__global__ __launch_bounds__(256, 3) void attn_k(
    const u16* __restrict__ Qs, const u16* __restrict__ Ks, const u16* __restrict__ Vs,
    float* __restrict__ Op, float* __restrict__ lp) {
    __shared__ u16 kbuf[2][5120];  // 10KB each; pair doubles as 20KB Q phase-1 staging
    __shared__ u16 vbuf[2][5120];  // 10KB each
    __shared__ u16 pls[4][1024];   // per-wave 16q x 64k transpose buffer

    const int t = threadIdx.x, lane = t & 63, w = t >> 6;
    const int qi = lane & 15, quad = lane >> 4;
    // XCD-local decode: all 16 q-blocks of an (h,ksp) combo on one XCD
    const int id = blockIdx.x;
    const int xcd = id & 7, sI = id >> 3;
    const int c = xcd * 6 + (sI >> 4);
    const int h = c & 15, ksp = c >> 4;
    const int q0 = (sI & 15) * QT;
    const int kc0 = ksp * KCHUNK;
    u16* const kflat = &kbuf[0][0];

    const u16* Qt = Qs + (size_t)(h * SEQ + q0) * 80;
    // Q phase 1: rows 0..127 (20KB)
    for (int j = 0; j < 5; j++) {
        int o = (w * 5 + j) * 512;
        gld16(Qt + o + lane * 8, kflat + o);
    }
    __syncthreads();
    short8 bq[3][3];
    auto qfrag = [&](const u16* basep, int rowl, int qg) {
        const u16* rb = &basep[rowl * 80];
        bq[qg][0] = *(const short8*)&rb[(quad ^ (qi & 7)) << 3];
        bq[qg][1] = *(const short8*)&rb[((4 + quad) ^ (qi & 7)) << 3];
        short4v t2 = *(const short4v*)&rb[((8 + ((quad >> 1) ^ ((qi >> 2) & 1))) << 3) + ((quad & 1) << 2)];
        bq[qg][2] = (short8){t2.x, t2.y, t2.z, t2.w, 0, 0, 0, 0};
    };
    for (int qg = 0; qg < 3; qg++) {
        int row0 = w * 48 + qg * 16;
        if (row0 < 128) qfrag(kflat, row0 + qi, qg);
    }
    __syncthreads();
    // Q phase 2: rows 128..191 (10KB into kbuf[0])
    for (int i = w; i < 10; i += 4)
        gld16(Qt + 128 * 80 + i * 512 + lane * 8, &kbuf[0][i * 512]);
    __syncthreads();
    for (int qg = 0; qg < 3; qg++) {
        int row0 = w * 48 + qg * 16;
        if (row0 >= 128) qfrag(&kbuf[0][0], row0 - 128 + qi, qg);
    }
    __syncthreads();

    float l_lane[3] = {0.f, 0.f, 0.f};
    floatx4 acco[3][5];
    for (int qg = 0; qg < 3; qg++)
        for (int dt = 0; dt < 5; dt++) acco[qg][dt] = (floatx4){0.f, 0.f, 0.f, 0.f};

    auto stage = [&](int it2, int buf) {
        int kc = kc0 + it2 * 64;
        const u16* Kt = Ks + (size_t)(h * SEQ + kc) * 80;
        for (int i = w; i < 10; i += 4)
            gld16(Kt + i * 512 + lane * 8, &kbuf[buf][i * 512]);
        const u16* Vt = Vs + (size_t)h * HD * SEQ + kc;
        for (int i = w; i < 10; i += 4) {
            int p16 = i * 64 + lane;
            int d = p16 >> 3, pc = p16 & 7;
            gld16(Vt + (size_t)d * SEQ + pc * 8, &vbuf[buf][i * 512]);
        }
    };
    stage(0, 0);
    __syncthreads();

    char* const myp = (char*)&pls[w][0];
    for (int it = 0; it < NT; it++) {
        int cur = it & 1;
        if (it + 1 < NT) stage(it + 1, cur ^ 1);
        const u16* kb = &kbuf[cur][0];
        const u16* vb = &vbuf[cur][0];
        for (int c2 = 0; c2 < 2; c2++) {
            short8 av[5];
            {
                int pvc = (4 * c2 + quad) ^ (qi & 7);
                for (int dt = 0; dt < 5; dt++)
                    av[dt] = *(const short8*)&vb[((dt * 16 + qi) * 8 + pvc) * 8];
            }
            uint2 pk2[2];
            for (int ktl = 0; ktl < 2; ktl++) {
                int arow = (c2 * 2 + ktl) * 16 + qi;
                const u16* rb = &kb[arow * 80];
                short8 a0 = *(const short8*)&rb[(quad ^ (qi & 7)) << 3];
                short8 a1 = *(const short8*)&rb[((4 + quad) ^ (qi & 7)) << 3];
                short4v a2v = *(const short4v*)&rb[((8 + ((quad >> 1) ^ ((qi >> 2) & 1))) << 3) + ((quad & 1) << 2)];
                short8 a2 = (short8){a2v.x, a2v.y, a2v.z, a2v.w, 0, 0, 0, 0};
                for (int qg = 0; qg < 3; qg++) {
                    floatx4 s = (floatx4){0.f, 0.f, 0.f, 0.f};
                    s = __builtin_amdgcn_mfma_f32_16x16x32_bf16(a0, bq[qg][0], s, 0, 0, 0);
                    s = __builtin_amdgcn_mfma_f32_16x16x32_bf16(a1, bq[qg][1], s, 0, 0, 0);
                    s = __builtin_amdgcn_mfma_f32_16x16x32_bf16(a2, bq[qg][2], s, 0, 0, 0);
                    float e0 = __builtin_amdgcn_exp2f(s[0]);
                    float e1 = __builtin_amdgcn_exp2f(s[1]);
                    float e2 = __builtin_amdgcn_exp2f(s[2]);
                    float e3 = __builtin_amdgcn_exp2f(s[3]);
                    l_lane[qg] += (e0 + e1) + (e2 + e3);
                    uint2 pk;
                    pk.x = __builtin_amdgcn_perm(__float_as_uint(e1), __float_as_uint(e0), 0x07060302u);
                    pk.y = __builtin_amdgcn_perm(__float_as_uint(e3), __float_as_uint(e2), 0x07060302u);
                    if (qg < 2) {
                        int chunk = qg * 4 + 2 * ktl + (quad >> 1);
                        *(uint2*)(myp + qi * 128 + ((chunk ^ (qi & 7)) << 4) + ((quad & 1) << 3)) = pk;
                    } else {
                        pk2[ktl] = pk;
                    }
                }
            }
            // round A: PV for qg0, qg1 (DS ops are wave-ordered; pls is wave-private)
            short8 bp0 = *(const short8*)(myp + qi * 128 + ((quad ^ (qi & 7)) << 4));
            short8 bp1 = *(const short8*)(myp + qi * 128 + (((4 + quad) ^ (qi & 7)) << 4));
            for (int dt = 0; dt < 5; dt++) {
                acco[0][dt] = __builtin_amdgcn_mfma_f32_16x16x32_bf16(av[dt], bp0, acco[0][dt], 0, 0, 0);
                acco[1][dt] = __builtin_amdgcn_mfma_f32_16x16x32_bf16(av[dt], bp1, acco[1][dt], 0, 0, 0);
            }
            // round B: qg2 reuses slot 0
            for (int ktl = 0; ktl < 2; ktl++) {
                int chunk = 2 * ktl + (quad >> 1);
                *(uint2*)(myp + qi * 128 + ((chunk ^ (qi & 7)) << 4) + ((quad & 1) << 3)) = pk2[ktl];
            }
            short8 bp2 = *(const short8*)(myp + qi * 128 + ((quad ^ (qi & 7)) << 4));
            for (int dt = 0; dt < 5; dt++)
                acco[2][dt] = __builtin_amdgcn_mfma_f32_16x16x32_bf16(av[dt], bp2, acco[2][dt], 0, 0, 0);
        }
        __syncthreads();
    }

    for (int qg = 0; qg < 3; qg++) {
        float lq = l_lane[qg];
        lq += __shfl_xor(lq, 16);
        lq += __shfl_xor(lq, 32);
        int q = q0 + w * 48 + qg * 16 + qi;
        if (quad == 0) lp[((size_t)ksp * NH + h) * SEQ + q] = lq;
        float* ob = &Op[(((size_t)ksp * NH + h) * SEQ + q) * HD];
        for (int dt = 0; dt < 5; dt++)
            *(floatx4*)&ob[dt * 16 + quad * 4] = acco[qg][dt];
    }
}

// ---------------- merge key-split partials -> att bf16 [SEQ][HID] ----------------
__global__ void merge_k(const float* __restrict__ Op, const float* __restrict__ lp,
                        u16* __restrict__ att) {
    int g = blockIdx.x * 256 + threadIdx.x;  // < 16*3072*20
    int h = g / (SEQ * 20);
    int r = g % (SEQ * 20);
    int q = r / 20, dg = r % 20;
    float sx = 0.f, sy = 0.f, sz = 0.f, sw = 0.f, l = 0.f;
    for (int ksp = 0; ksp < KSP; ksp++) {
        const float4 v = *(const float4*)&Op[(((size_t)ksp * NH + h) * SEQ + q) * HD + dg * 4];
        sx += v.x; sy += v.y; sz += v.z; sw += v.w;
        l += lp[((size_t)ksp * NH + h) * SEQ + q];
    }
    float li = 1.0f / l;
    uint2 o;
    o.x = packrne(sx * li, sy * li);
    o.y = packrne(sz * li, sw * li);
    *(uint2*)&att[(size_t)q * HID + h * HD + dg * 4] = o;
}

extern "C" void kernel_launch(void* const* d_in, const int* in_sizes, int n_in,
                              void* d_out, int out_size, void* d_ws, size_t ws_size,
                              hipStream_t stream) {
    const float* hs   = (const float*)d_in[0];
    const int*   pos  = (const int*)d_in[1];
    const float* qkvw = (const float*)d_in[2];
    const float* qkvb = (const float*)d_in[3];
    const float* ow   = (const float*)d_in[4];
    const float* ob   = (const float*)d_in[5];
    float* out = (float*)d_out;

    char* p = (char*)d_ws;
    auto alloc = [&](size_t bytes) {
        char* r = p;
        p += (bytes + 255) & ~(size_t)255;
        return r;
    };
    float* cosb = (float*)alloc((size_t)SEQ * 40 * 4);
    float* sinb = (float*)alloc((size_t)SEQ * 40 * 4);
    u16* owT = (u16*)alloc((size_t)HID * HID * 2);
    // pool1: phase A = hidden bf16 + qkv_w^T bf16; phase B = Qs + Ks (aliased)
    char* pool1 = alloc(7864320 + 9830400);
    u16* hH = (u16*)pool1;
    u16* wT = (u16*)(pool1 + 7864320);
    u16* Qs = (u16*)pool1;                    // phase B: 16*3072*80*2 = 7864320
    u16* Ks = (u16*)(pool1 + 7864320);
    // pool2: phase A = qkv f32 (47.2MB); phase B = att bf16 + Op f32 partials + lp
    char* pool2 = alloc(55640320);
    float* qkv_s = (float*)pool2;
    u16* att  = (u16*)pool2;
    float* Op = (float*)(pool2 + 7864320);
    float* lp = (float*)(pool2 + 7864320 + 47185920);
    u16* Vs = (u16*)alloc((size_t)NH * HD * SEQ * 2);

    hipLaunchKernelGGL(prep_k, dim3(10720), dim3(256), 0, stream,
                       pos, cosb, sinb, hs, hH, qkvw, wT, ow, owT);
    hipLaunchKernelGGL(gemm_bf16_k, dim3(720), dim3(256), 0, stream,
                       hH, wT, qkvb, qkv_s, SEQ, NQKV, HID, 0);
    hipLaunchKernelGGL(pack_qkv_k, dim3(SEQ / 64, NH), dim3(256), 0, stream,
                       qkv_s, cosb, sinb, Qs, Ks, Vs);
    hipLaunchKernelGGL(attn_k, dim3(768), dim3(256), 0, stream,
                       Qs, Ks, Vs, Op, lp);
    hipLaunchKernelGGL(merge_k, dim3(3840), dim3(256), 0, stream, Op, lp, att);
    hipLaunchKernelGGL(gemm_bf16_k, dim3(240), dim3(256), 0, stream,
                       att, owT, ob, out, SEQ, HID, HID, 1);
}

// Round 7
// 232.360 us; speedup vs baseline: 1.6888x; 1.6888x over previous
//
#include <hip/hip_runtime.h>

#define SEQ  3072
#define HID  1280
#define NH   16
#define HD   80
#define NQKV 3840
#define KSP  2

typedef unsigned short u16;
typedef unsigned int u32;
typedef __attribute__((ext_vector_type(8))) short short8;
typedef __attribute__((ext_vector_type(4))) short short4v;
typedef __attribute__((ext_vector_type(4))) float floatx4;

__device__ __forceinline__ u16 f2bf(float x) {
    u32 u = __float_as_uint(x);
    u += 0x7fffu + ((u >> 16) & 1u);
    return (u16)(u >> 16);
}
__device__ __forceinline__ u32 packrne(float a, float b) {
    return (u32)f2bf(a) | ((u32)f2bf(b) << 16);
}

typedef const __attribute__((address_space(1))) unsigned int* gp1_t;
typedef __attribute__((address_space(3))) unsigned int* lp3_t;
__device__ __forceinline__ void gld16(const void* g, void* l) {
    __builtin_amdgcn_global_load_lds((gp1_t)g, (lp3_t)l, 16, 0, 0);
}

// swizzled 16B-chunk position for 80-dim Q/K rows (10 chunks / 160B):
// main chunks 0..7: ^(r&7); tail 8..9: ^((r>>2)&1)
__device__ __forceinline__ int swz80(int c, int r) {
    return (c < 8) ? (c ^ (r & 7)) : (8 + ((c - 8) ^ ((r >> 2) & 1)));
}

// ---------------- fused prep: rope tables | cast hidden | transpose qkv_w | transpose o_w ----------------
__global__ void prep_k(const int* __restrict__ pos, float* __restrict__ cosb,
                       float* __restrict__ sinb, const float* __restrict__ hs,
                       u16* __restrict__ hH, const float* __restrict__ qkvw,
                       u16* __restrict__ wT, const float* __restrict__ ow,
                       u16* __restrict__ owT) {
    __shared__ float tile[32][33];
    const int b = blockIdx.x, t = threadIdx.x;
    if (b < 480) {  // rope tables: 3072 x 40
        int i = b * 256 + t;
        int s = i / 40, j = i % 40;
        float p = (float)((j < 20) ? pos[s * 2] : pos[s * 2 + 1]);
        int k = (j < 20) ? j : j - 20;
        float inv = powf(10000.0f, -(float)k / 20.0f);
        float a = p * inv;
        cosb[s * 40 + j] = cosf(a);
        sinb[s * 40 + j] = sinf(a);
    } else if (b < 4320) {  // cast hidden f32 -> bf16, vec4
        int i = (b - 480) * 256 + t;  // < 983040
        const float4 x = ((const float4*)hs)[i];
        uint2 o;
        o.x = packrne(x.x, x.y);
        o.y = packrne(x.z, x.w);
        ((uint2*)hH)[i] = o;
    } else {
        const float* w;
        u16* dst;
        int K, N, nx, ky;
        if (b < 9120) {
            int i = b - 4320;
            nx = i % 120; ky = i / 120; w = qkvw; dst = wT; K = HID; N = NQKV;
        } else {
            int i = b - 9120;
            nx = i % 40; ky = i / 40; w = ow; dst = owT; K = HID; N = HID;
        }
        int n0 = nx * 32, k0 = ky * 32;
        int c = t & 31, r8 = t >> 5;
        for (int rr = r8; rr < 32; rr += 8)
            tile[rr][c] = w[(size_t)(k0 + rr) * N + n0 + c];
        __syncthreads();
        for (int rr = r8; rr < 32; rr += 8)
            dst[(size_t)(n0 + rr) * K + k0 + c] = f2bf(tile[c][rr]);
    }
}

// ---------------- bf16 GEMM: C[M][N] = A[M][K] * Bt[N][K]^T + bias, XCD-patched 1D grid ----------------
__global__ __launch_bounds__(256, 3) void gemm_bf16_k(
    const u16* __restrict__ A, const u16* __restrict__ B,
    const float* __restrict__ bias, float* __restrict__ C,
    int M, int N, int K, int mode) {
    __shared__ u16 lA[128 * 64], lB[128 * 64];
    const int t = threadIdx.x, lane = t & 63, w = t >> 6;
    const int qi = lane & 15, quad = lane >> 4;
    int id = blockIdx.x;
    int xcd = id & 7, sN = id >> 3;
    int m_idx, n_idx;
    if (mode == 0) {  // QKV: 30n x 24m tiles, 15x6 patch per XCD
        n_idx = (xcd & 1) * 15 + sN % 15;
        m_idx = (xcd >> 1) * 6 + sN / 15;
    } else {          // O-proj: 10n x 24m tiles, 10x3 patch per XCD
        m_idx = xcd * 3 + sN / 10;
        n_idx = sN % 10;
    }
    const int m0 = m_idx * 128, n0 = n_idx * 128;
    const int wm = (w >> 1) * 64, wn = (w & 1) * 64;

    floatx4 acc[4][4];
    for (int mi = 0; mi < 4; mi++)
        for (int ni = 0; ni < 4; ni++) acc[mi][ni] = (floatx4){0.f, 0.f, 0.f, 0.f};

    const int rg = lane >> 3;
    const int ce = ((lane & 7) ^ rg) * 8;
    size_t gA[4], gB[4];
    for (int g = 0; g < 4; g++) {
        int row = w * 32 + g * 8 + rg;
        gA[g] = (size_t)(m0 + row) * K + ce;
        gB[g] = (size_t)(n0 + row) * K + ce;
    }

    for (int k0 = 0; k0 < K; k0 += 64) {
        for (int g = 0; g < 4; g++) {
            gld16(A + gA[g] + k0, &lA[(w * 32 + g * 8) * 64]);
            gld16(B + gB[g] + k0, &lB[(w * 32 + g * 8) * 64]);
        }
        __syncthreads();
        short8 af[4][2], bf[4][2];
        for (int mi = 0; mi < 4; mi++) {
            int row = wm + mi * 16 + qi;
            for (int kh = 0; kh < 2; kh++)
                af[mi][kh] = *(const short8*)&lA[row * 64 + (((kh * 4 + quad) ^ (row & 7)) << 3)];
        }
        for (int ni = 0; ni < 4; ni++) {
            int row = wn + ni * 16 + qi;
            for (int kh = 0; kh < 2; kh++)
                bf[ni][kh] = *(const short8*)&lB[row * 64 + (((kh * 4 + quad) ^ (row & 7)) << 3)];
        }
        for (int mi = 0; mi < 4; mi++)
            for (int ni = 0; ni < 4; ni++) {
                acc[mi][ni] = __builtin_amdgcn_mfma_f32_16x16x32_bf16(af[mi][0], bf[ni][0], acc[mi][ni], 0, 0, 0);
                acc[mi][ni] = __builtin_amdgcn_mfma_f32_16x16x32_bf16(af[mi][1], bf[ni][1], acc[mi][ni], 0, 0, 0);
            }
        __syncthreads();
    }
    for (int mi = 0; mi < 4; mi++)
        for (int ni = 0; ni < 4; ni++) {
            int col = n0 + wn + ni * 16 + qi;
            int rowb = m0 + wm + mi * 16 + quad * 4;
            float b = bias[col];
            for (int r = 0; r < 4; r++)
                C[(size_t)(rowb + r) * N + col] = acc[mi][ni][r] + b;
        }
}

// ---------------- pack: rope Q (x scale x log2e), K -> swizzled [h][s][80]; V -> swizzled Vt ----------------
__global__ void pack_qkv_k(const float* __restrict__ qkv, const float* __restrict__ cosb,
                           const float* __restrict__ sinb,
                           u16* __restrict__ Qs, u16* __restrict__ Ks, u16* __restrict__ Vs) {
    __shared__ float lv[80 * 65];
    const int t = threadIdx.x;
    const int h = blockIdx.y, s0 = blockIdx.x * 64;
    const float qsc = 0.11180339887498949f * 1.4426950408889634f;  // 80^-0.5 * log2(e)

    for (int i = t; i < 64 * 10; i += 256) {
        int rl = i / 10, jg = i % 10;
        int s = s0 + rl, j = jg * 4;
        const float4 cc = *(const float4*)&cosb[s * 40 + j];
        const float4 ss = *(const float4*)&sinb[s * 40 + j];
        const float* qb = qkv + (size_t)s * NQKV + h * HD;
        const float4 q1 = *(const float4*)&qb[j];
        const float4 q2 = *(const float4*)&qb[j + 40];
        const float* kb = qb + HID;
        const float4 k1 = *(const float4*)&kb[j];
        const float4 k2 = *(const float4*)&kb[j + 40];
        uint2 qo1, qo2, ko1, ko2;
        qo1.x = packrne((q1.x * cc.x - q2.x * ss.x) * qsc, (q1.y * cc.y - q2.y * ss.y) * qsc);
        qo1.y = packrne((q1.z * cc.z - q2.z * ss.z) * qsc, (q1.w * cc.w - q2.w * ss.w) * qsc);
        qo2.x = packrne((q2.x * cc.x + q1.x * ss.x) * qsc, (q2.y * cc.y + q1.y * ss.y) * qsc);
        qo2.y = packrne((q2.z * cc.z + q1.z * ss.z) * qsc, (q2.w * cc.w + q1.w * ss.w) * qsc);
        ko1.x = packrne(k1.x * cc.x - k2.x * ss.x, k1.y * cc.y - k2.y * ss.y);
        ko1.y = packrne(k1.z * cc.z - k2.z * ss.z, k1.w * cc.w - k2.w * ss.w);
        ko2.x = packrne(k2.x * cc.x + k1.x * ss.x, k2.y * cc.y + k1.y * ss.y);
        ko2.y = packrne(k2.z * cc.z + k1.z * ss.z, k2.w * cc.w + k1.w * ss.w);
        size_t base = (size_t)(h * SEQ + s) * 80;
        int sub0 = j & 7, sub1 = (j + 40) & 7;
        int p0 = swz80(j >> 3, s);
        int p1 = swz80((j + 40) >> 3, s);
        *(uint2*)&Qs[base + p0 * 8 + sub0] = qo1;
        *(uint2*)&Qs[base + p1 * 8 + sub1] = qo2;
        *(uint2*)&Ks[base + p0 * 8 + sub0] = ko1;
        *(uint2*)&Ks[base + p1 * 8 + sub1] = ko2;
    }
    for (int i = t; i < 64 * 80; i += 256) {
        int rl = i / 80, d = i % 80;
        lv[d * 65 + rl] = qkv[(size_t)(s0 + rl) * NQKV + 2 * HID + h * HD + d];
    }
    __syncthreads();
    for (int i = t; i < 80 * 16; i += 256) {
        int d = i / 16, g = i % 16;
        int c2l = g * 4;
        float v0 = lv[d * 65 + c2l], v1 = lv[d * 65 + c2l + 1];
        float v2 = lv[d * 65 + c2l + 2], v3 = lv[d * 65 + c2l + 3];
        int pc = (g >> 1) ^ (d & 7);
        uint2 o;
        o.x = packrne(v0, v1);
        o.y = packrne(v2, v3);
        *(uint2*)&Vs[((size_t)h * HD + d) * SEQ + s0 + pc * 8 + (g & 1) * 4] = o;
    }
}

// ---------------- flash attention: QT=128, key-split 2, no-max exp2 softmax, 80-dim rows ----------------
__global__ __launch_bounds__(256, 3) void attn_k(
    const u16* __restrict__ Qs, const u16* __restrict__ Ks, const u16* __restrict__ Vs,
    float* __restrict__ Op, float* __restrict__ lp) {
    __shared__ u16 kbuf[2][5120];  // 10KB each; pair doubles as 20KB Q staging
    __shared__ u16 vbuf[2][5120];  // 10KB each
    __shared__ u16 pls[4][1024];   // per-wave 16q x 64k (2 qg interleaved), 128B rows

    const int t = threadIdx.x, lane = t & 63, w = t >> 6;
    const int qi = lane & 15, quad = lane >> 4;
    const int h = blockIdx.y, q0 = blockIdx.x * 128, ksp = blockIdx.z;
    const int kc0 = ksp * (SEQ / 2);
    u16* const kflat = &kbuf[0][0];

    {   // stage Q: 128 rows x 160B = 20KB across the kbuf pair
        const u16* Qt = Qs + (size_t)(h * SEQ + q0) * 80;
        for (int j = 0; j < 5; j++) {
            int o = (w * 5 + j) * 512;
            gld16(Qt + o + lane * 8, kflat + o);
        }
    }
    __syncthreads();
    short8 bq[2][3];
    for (int qg = 0; qg < 2; qg++) {
        const u16* rb = &kflat[(w * 32 + qg * 16 + qi) * 80];
        bq[qg][0] = *(const short8*)&rb[(quad ^ (qi & 7)) << 3];
        bq[qg][1] = *(const short8*)&rb[((4 + quad) ^ (qi & 7)) << 3];
        short4v t2 = *(const short4v*)&rb[((8 + ((quad >> 1) ^ ((qi >> 2) & 1))) << 3) + ((quad & 1) << 2)];
        bq[qg][2] = (short8){t2.x, t2.y, t2.z, t2.w, 0, 0, 0, 0};
    }
    __syncthreads();

    float l_lane[2] = {0.f, 0.f};
    floatx4 acco[2][5];
    for (int qg = 0; qg < 2; qg++)
        for (int dt = 0; dt < 5; dt++) acco[qg][dt] = (floatx4){0.f, 0.f, 0.f, 0.f};

    auto stage = [&](int it, int buf) {
        int kc = kc0 + it * 64;
        const u16* Kt = Ks + (size_t)(h * SEQ + kc) * 80;
        for (int i = w; i < 10; i += 4)
            gld16(Kt + i * 512 + lane * 8, &kbuf[buf][i * 512]);
        const u16* Vt = Vs + (size_t)h * HD * SEQ + kc;
        for (int i = w; i < 10; i += 4) {
            int p16 = i * 64 + lane;
            int d = p16 >> 3, pc = p16 & 7;
            gld16(Vt + (size_t)d * SEQ + pc * 8, &vbuf[buf][i * 512]);
        }
    };
    stage(0, 0);
    __syncthreads();

    const int NT = (SEQ / 2) / 64;  // 24
    char* const myp = (char*)&pls[w][0];
    for (int it = 0; it < NT; it++) {
        int cur = it & 1;
        if (it + 1 < NT) stage(it + 1, cur ^ 1);
        const u16* kb = &kbuf[cur][0];
        const u16* vb = &vbuf[cur][0];
        for (int c2 = 0; c2 < 2; c2++) {
            for (int ktl = 0; ktl < 2; ktl++) {
                int arow = (c2 * 2 + ktl) * 16 + qi;
                const u16* rb = &kb[arow * 80];
                short8 a0 = *(const short8*)&rb[(quad ^ (qi & 7)) << 3];
                short8 a1 = *(const short8*)&rb[((4 + quad) ^ (qi & 7)) << 3];
                short4v a2v = *(const short4v*)&rb[((8 + ((quad >> 1) ^ ((qi >> 2) & 1))) << 3) + ((quad & 1) << 2)];
                short8 a2 = (short8){a2v.x, a2v.y, a2v.z, a2v.w, 0, 0, 0, 0};
                for (int qg = 0; qg < 2; qg++) {
                    floatx4 s = (floatx4){0.f, 0.f, 0.f, 0.f};
                    s = __builtin_amdgcn_mfma_f32_16x16x32_bf16(a0, bq[qg][0], s, 0, 0, 0);
                    s = __builtin_amdgcn_mfma_f32_16x16x32_bf16(a1, bq[qg][1], s, 0, 0, 0);
                    s = __builtin_amdgcn_mfma_f32_16x16x32_bf16(a2, bq[qg][2], s, 0, 0, 0);
                    float e0 = __builtin_amdgcn_exp2f(s[0]);
                    float e1 = __builtin_amdgcn_exp2f(s[1]);
                    float e2 = __builtin_amdgcn_exp2f(s[2]);
                    float e3 = __builtin_amdgcn_exp2f(s[3]);
                    l_lane[qg] += (e0 + e1) + (e2 + e3);
                    uint2 pk;
                    pk.x = __builtin_amdgcn_perm(__float_as_uint(e1), __float_as_uint(e0), 0x07060302u);
                    pk.y = __builtin_amdgcn_perm(__float_as_uint(e3), __float_as_uint(e2), 0x07060302u);
                    int chunk = qg * 4 + 2 * ktl + (quad >> 1);
                    *(uint2*)(myp + qi * 128 + ((chunk ^ (qi & 7)) << 4) + ((quad & 1) << 3)) = pk;
                }
            }
            short8 bp0 = *(const short8*)(myp + qi * 128 + (((quad) ^ (qi & 7)) << 4));
            short8 bp1 = *(const short8*)(myp + qi * 128 + (((4 + quad) ^ (qi & 7)) << 4));
            int pv = (4 * c2 + quad) ^ (qi & 7);
            for (int dt = 0; dt < 5; dt++) {
                short8 av = *(const short8*)&vb[((dt * 16 + qi) * 8 + pv) * 8];
                acco[0][dt] = __builtin_amdgcn_mfma_f32_16x16x32_bf16(av, bp0, acco[0][dt], 0, 0, 0);
                acco[1][dt] = __builtin_amdgcn_mfma_f32_16x16x32_bf16(av, bp1, acco[1][dt], 0, 0, 0);
            }
        }
        __syncthreads();
    }

    for (int qg = 0; qg < 2; qg++) {
        float lq = l_lane[qg];
        lq += __shfl_xor(lq, 16);
        lq += __shfl_xor(lq, 32);
        int q = q0 + w * 32 + qg * 16 + qi;
        if (quad == 0) lp[(size_t)(ksp * NH + h) * SEQ + q] = lq;
        for (int dt = 0; dt < 5; dt++)
            for (int r = 0; r < 4; r++) {
                int d = dt * 16 + quad * 4 + r;
                Op[((size_t)(ksp * NH + h) * HD + d) * SEQ + q] = acco[qg][dt][r];
            }
    }
}

// ---------------- merge key-split partials -> att bf16 [SEQ][HID] ----------------
__global__ void merge_k(const float* __restrict__ Op, const float* __restrict__ lp,
                        u16* __restrict__ att) {
    __shared__ float ls[HD * 65];
    __shared__ float li[64];
    const int t = threadIdx.x;
    const int h = blockIdx.y, q0 = blockIdx.x * 64;
    for (int i = t; i < HD * 16; i += 256) {
        int d = i / 16, g = i % 16;
        size_t a0 = ((size_t)h * HD + d) * SEQ + q0 + g * 4;
        size_t a1 = ((size_t)(NH + h) * HD + d) * SEQ + q0 + g * 4;
        const float4 v0 = *(const float4*)&Op[a0];
        const float4 v1 = *(const float4*)&Op[a1];
        ls[d * 65 + g * 4 + 0] = v0.x + v1.x;
        ls[d * 65 + g * 4 + 1] = v0.y + v1.y;
        ls[d * 65 + g * 4 + 2] = v0.z + v1.z;
        ls[d * 65 + g * 4 + 3] = v0.w + v1.w;
    }
    if (t < 64)
        li[t] = 1.0f / (lp[(size_t)h * SEQ + q0 + t] + lp[(size_t)(NH + h) * SEQ + q0 + t]);
    __syncthreads();
    for (int i = t; i < 64 * 40; i += 256) {
        int ql = i / 40, dg = i % 40;
        int d0 = dg * 2;
        float s = li[ql];
        u32 o = packrne(ls[d0 * 65 + ql] * s, ls[(d0 + 1) * 65 + ql] * s);
        *(u32*)&att[(size_t)(q0 + ql) * HID + h * HD + d0] = o;
    }
}

extern "C" void kernel_launch(void* const* d_in, const int* in_sizes, int n_in,
                              void* d_out, int out_size, void* d_ws, size_t ws_size,
                              hipStream_t stream) {
    const float* hs   = (const float*)d_in[0];
    const int*   pos  = (const int*)d_in[1];
    const float* qkvw = (const float*)d_in[2];
    const float* qkvb = (const float*)d_in[3];
    const float* ow   = (const float*)d_in[4];
    const float* ob   = (const float*)d_in[5];
    float* out = (float*)d_out;

    char* p = (char*)d_ws;
    auto alloc = [&](size_t bytes) {
        char* r = p;
        p += (bytes + 255) & ~(size_t)255;
        return r;
    };
    float* cosb = (float*)alloc((size_t)SEQ * 40 * 4);
    float* sinb = (float*)alloc((size_t)SEQ * 40 * 4);
    u16* owT = (u16*)alloc((size_t)HID * HID * 2);
    // pool1: phase A = hidden bf16 + qkv_w^T bf16; phase B = Qs + Ks (aliased, 80-dim)
    char* pool1 = alloc(7864320 + 9830400);
    u16* hH = (u16*)pool1;
    u16* wT = (u16*)(pool1 + 7864320);
    u16* Qs = (u16*)pool1;                    // phase B: 16*3072*80*2 = 7864320
    u16* Ks = (u16*)(pool1 + 7864320);
    // pool2: phase A = qkv f32; phase B = att bf16 + Op f32 partials + lp
    char* pool2 = alloc((size_t)SEQ * NQKV * 4);
    float* qkv_s = (float*)pool2;
    u16* att  = (u16*)pool2;
    float* Op = (float*)(pool2 + 7864320);
    float* lp = (float*)(pool2 + 39321600);
    u16* Vs = (u16*)alloc((size_t)NH * HD * SEQ * 2);

    hipLaunchKernelGGL(prep_k, dim3(10720), dim3(256), 0, stream,
                       pos, cosb, sinb, hs, hH, qkvw, wT, ow, owT);
    hipLaunchKernelGGL(gemm_bf16_k, dim3(720), dim3(256), 0, stream,
                       hH, wT, qkvb, qkv_s, SEQ, NQKV, HID, 0);
    hipLaunchKernelGGL(pack_qkv_k, dim3(SEQ / 64, NH), dim3(256), 0, stream,
                       qkv_s, cosb, sinb, Qs, Ks, Vs);
    hipLaunchKernelGGL(attn_k, dim3(SEQ / 128, NH, 2), dim3(256), 0, stream,
                       Qs, Ks, Vs, Op, lp);
    hipLaunchKernelGGL(merge_k, dim3(SEQ / 64, NH), dim3(256), 0, stream, Op, lp, att);
    hipLaunchKernelGGL(gemm_bf16_k, dim3(240), dim3(256), 0, stream,
                       att, owT, ob, out, SEQ, HID, HID, 1);
}